// Round 1
// baseline (412.760 us; speedup 1.0000x reference)
//
#include <hip/hip_runtime.h>

// QuadConv: out[p,:] = concat_j feat[nidx[p,j],:] (1152) @ W.T (128x1152) + b
// Strategy: bf16 MFMA GEMM (32x32x16), W pre-packed to fragment order in d_ws,
// per-block LDS staging of W j-slabs via global_load_lds, A gathered fp32->bf16.

#define NPTS    262144
#define CIN     128
#define COUT    128
#define KNBR    9
#define KDIM    (KNBR * CIN)     // 1152
#define NKS     (KDIM / 16)      // 72 K-steps of 16
#define NFRAGS  (NKS * 4)        // 288 fragments of 1 KiB (64 lanes x 16 B)
#define MT      128              // rows per block (4 waves x 32)

typedef __bf16  bf16x8 __attribute__((ext_vector_type(8)));
typedef float   f32x4  __attribute__((ext_vector_type(4)));
typedef float   f32x16 __attribute__((ext_vector_type(16)));

// Pack W [128 x 1152] fp32 -> bf16 in MFMA B-fragment order:
// frag = ks*4 + nt; element (frag*512 + lane*8 + i) = W[nt*32+(lane&31)][ks*16+(lane>>5)*8+i]
__global__ __launch_bounds__(256) void pack_w_kernel(const float* __restrict__ W,
                                                     __bf16* __restrict__ Wp) {
    int t    = blockIdx.x * 256 + threadIdx.x;   // 0 .. NFRAGS*64-1
    int lane = t & 63;
    int frag = t >> 6;
    if (frag >= NFRAGS) return;
    int nt = frag & 3;
    int ks = frag >> 2;
    int n  = nt * 32 + (lane & 31);
    int k0 = ks * 16 + (lane >> 5) * 8;
    const f32x4* src = (const f32x4*)(W + (size_t)n * KDIM + k0);
    f32x4 v0 = src[0], v1 = src[1];
    bf16x8 o;
#pragma unroll
    for (int i = 0; i < 4; ++i) { o[i] = (__bf16)v0[i]; o[i + 4] = (__bf16)v1[i]; }
    *(bf16x8*)(Wp + (size_t)frag * 512 + lane * 8) = o;
}

__global__ __launch_bounds__(256, 4) void qconv_kernel(
    const float*  __restrict__ feat,   // [NPTS, 128] fp32
    const int*    __restrict__ nidx,   // [NPTS, 9] int32
    const __bf16* __restrict__ Wp,     // packed fragments, 288 KiB
    const float*  __restrict__ bias,   // [128]
    float*        __restrict__ out)    // [NPTS, 128]
{
    __shared__ __align__(16) __bf16 lds[32 * 512];   // 32 KiB: one j-slab (32 frags)

    const int tid  = threadIdx.x;
    const int lane = tid & 63;
    const int wave = tid >> 6;
    const int l31  = lane & 31;
    const int half = lane >> 5;
    const int row_base = blockIdx.x * MT + wave * 32;
    const int p = row_base + l31;          // point this lane gathers for (A row m = l31)

    f32x16 acc[4];
#pragma unroll
    for (int nt = 0; nt < 4; ++nt)
#pragma unroll
        for (int i = 0; i < 16; ++i) acc[nt][i] = 0.f;

    const int* nrow = nidx + (size_t)p * KNBR;

    for (int j = 0; j < KNBR; ++j) {
        // Stage W j-slab (32 KiB) into LDS; wave stages frags [wave*8, wave*8+8)
#pragma unroll
        for (int f8 = 0; f8 < 8; ++f8) {
            const int f = wave * 8 + f8;
            const __bf16* g = Wp + (size_t)(j * 32 + f) * 512 + lane * 8;
            __builtin_amdgcn_global_load_lds(
                (const __attribute__((address_space(1))) void*)g,
                (__attribute__((address_space(3))) void*)(lds + f * 512),
                16, 0, 0);
        }
        const int gi = nrow[j];
        const bool valid = gi >= 0;
        const float* arow = feat + (size_t)(valid ? gi : 0) * CIN;
        __syncthreads();   // drains vmcnt -> LDS ready

#pragma unroll
        for (int ks = 0; ks < 8; ++ks) {
            const int c0 = ks * 16 + half * 8;   // channel base for this lane's 8 elems
            f32x4 a0 = {0.f, 0.f, 0.f, 0.f}, a1 = {0.f, 0.f, 0.f, 0.f};
            if (valid) {
                const f32x4* ap = (const f32x4*)(arow + c0);
                a0 = ap[0];
                a1 = ap[1];
            }
            bf16x8 afrag;
#pragma unroll
            for (int i = 0; i < 4; ++i) { afrag[i] = (__bf16)a0[i]; afrag[i + 4] = (__bf16)a1[i]; }
#pragma unroll
            for (int nt = 0; nt < 4; ++nt) {
                bf16x8 bfrag = *(const bf16x8*)(lds + (ks * 4 + nt) * 512 + lane * 8);
                acc[nt] = __builtin_amdgcn_mfma_f32_32x32x16_bf16(afrag, bfrag, acc[nt], 0, 0, 0);
            }
        }
        __syncthreads();
    }

    // Epilogue: C/D layout col=lane&31, row=(r&3)+8*(r>>2)+4*half  [verified m74/m101]
#pragma unroll
    for (int nt = 0; nt < 4; ++nt) {
        const int col = nt * 32 + l31;
        const float bv = bias[col];
#pragma unroll
        for (int r = 0; r < 16; ++r) {
            const int row = (r & 3) + 8 * (r >> 2) + 4 * half;
            out[(size_t)(row_base + row) * COUT + col] = acc[nt][r] + bv;
        }
    }
}

extern "C" void kernel_launch(void* const* d_in, const int* in_sizes, int n_in,
                              void* d_out, int out_size, void* d_ws, size_t ws_size,
                              hipStream_t stream) {
    const float* feat = (const float*)d_in[0];
    const int*   nidx = (const int*)d_in[1];
    const float* W    = (const float*)d_in[2];
    const float* bias = (const float*)d_in[3];
    float*       out  = (float*)d_out;
    __bf16*      Wp   = (__bf16*)d_ws;          // 288 KiB scratch

    pack_w_kernel<<<NFRAGS / 4, 256, 0, stream>>>(W, Wp);           // 72 blocks
    qconv_kernel<<<NPTS / MT, 256, 0, stream>>>(feat, nidx, Wp, bias, out);  // 2048 blocks
}